// Round 6
// baseline (164.370 us; speedup 1.0000x reference)
//
#include <hip/hip_runtime.h>
#include <float.h>

#define Bb 2
#define Ll 256
#define Ss 384
#define Hh 768
#define Tc 16
#define Dc 50
#define WD 100
#define CV 128
#define NG 200     // 4*Dc gates
#define OUTC 968   // H + WD + 2*Dc

// ws layout (floats):
//   [0, 128)      minv partials
//   [128, ...)    xproj table [2][128][200], bias folded in

__device__ inline float tanh_fast(float x) {
    float e = __expf(2.f * x);
    return 1.f - 2.f / (e + 1.f);
}
__device__ inline float sigmoid_fast(float x) {
    return 1.f / (1.f + __expf(-x));
}

// ================= kernel 1: min partials | xproj =================
// grid 144: [0,128) min, [128,144) xproj

__global__ __launch_bounds__(256) void kernel1(
        const float* __restrict__ bert, const float* __restrict__ char_table,
        const float* __restrict__ Wih_f, const float* __restrict__ bih_f, const float* __restrict__ bhh_f,
        const float* __restrict__ Wih_b, const float* __restrict__ bih_b, const float* __restrict__ bhh_b,
        float* __restrict__ minp, float* __restrict__ xpt) {
    int blk = blockIdx.x, tid = threadIdx.x;
    if (blk < 128) {
        const int n4 = (Bb * Ss * Hh) / 4;       // 147456 float4
        const float4* b4 = (const float4*)bert;
        float m = FLT_MAX;
        for (int i = blk * 256 + tid; i < n4; i += 128 * 256) {
            float4 v = b4[i];
            m = fminf(m, fminf(fminf(v.x, v.y), fminf(v.z, v.w)));
        }
        #pragma unroll
        for (int off = 32; off; off >>= 1) m = fminf(m, __shfl_down(m, off, 64));
        __shared__ float red[4];
        if ((tid & 63) == 0) red[tid >> 6] = m;
        __syncthreads();
        if (tid == 0) minp[blk] = fminf(fminf(red[0], red[1]), fminf(red[2], red[3]));
    } else {
        int idx = blk - 128;            // dir*8 + cid-chunk
        int dir = idx >> 3, c0 = (idx & 7) * 16;
        const float* Wih = dir ? Wih_b : Wih_f;
        const float* bih = dir ? bih_b : bih_f;
        const float* bhh = dir ? bhh_b : bhh_f;
        __shared__ float ct[16][Dc];
        for (int e = tid; e < 16 * Dc; e += 256)
            ((float*)ct)[e] = char_table[c0 * Dc + e];
        __syncthreads();
        if (tid < NG) {
            float w[Dc];
            #pragma unroll
            for (int j = 0; j < Dc; j++) w[j] = Wih[tid * Dc + j];
            float bias = bih[tid] + bhh[tid];
            for (int cid = 0; cid < 16; cid++) {
                float a = bias;
                #pragma unroll
                for (int j = 0; j < Dc; j++) a += w[j] * ct[cid][j];
                xpt[(dir * CV + c0 + cid) * NG + tid] = a;
            }
        }
    }
}

// ================= kernel_lstm: char bi-LSTM =================
// grid 1024: n = blk>>1, dir = blk&1. Own kernel => own register allocation.
// launch_bounds(256,4): min 4 waves/EU = 4 blocks/CU (our exact residency),
// VGPR cap 128 -- room for the w[52] weight set the fused kernel's 40-reg
// allocation kept spilling/rematerializing.

__global__ __launch_bounds__(256, 4) void kernel_lstm(
        const int* __restrict__ char_ids, const int* __restrict__ char_count,
        const float* __restrict__ Whh_f, const float* __restrict__ Whh_b,
        const float* __restrict__ xpt, float* __restrict__ out) {
    __shared__ __align__(16) char smem[13888];
    int blk = blockIdx.x, tid = threadIdx.x;

    float (*xg)[NG] = (float (*)[NG])smem;            // 16*200*4 = 12800
    float* gs  = (float*)(smem + 12800);              // 800
    float* hs  = (float*)(smem + 13600);              // 208 (52 floats)
    int*   scid = (int*)(smem + 13808);               // 64

    int n = blk >> 1, dir = blk & 1;
    const float* Whh = dir ? Whh_b : Whh_f;

    int len = char_count[n];
    if (len < 1) len = 1;
    if (tid < Tc) {
        int t = tid;
        int st = dir ? (t < len ? len - 1 - t : t) : t;   // bwd: reverse valid prefix
        scid[t] = char_ids[n * Tc + st];
    }
    if (tid < 52) hs[tid] = 0.f;
    __syncthreads();

    // stage xproj rows as float4 (row stride 200 floats = 800B, 16B aligned)
    for (int e = tid; e < Tc * (NG / 4); e += 256) {
        int t = e / 50, q = e - t * 50;
        ((float4*)xg[t])[q] = ((const float4*)&xpt[(dir * CV + scid[t]) * NG])[q];
    }
    // recurrent weight row -> regs, defined for ALL lanes (clamped row)
    int wrow = tid < NG ? tid : NG - 1;
    bool istanh = (tid >= 100 && tid < 150);          // cell-gate rows
    float w[52];
    #pragma unroll
    for (int j = 0; j < Dc; j++) w[j] = Whh[wrow * Dc + j];
    w[50] = 0.f; w[51] = 0.f;
    __syncthreads();

    float c = 0.f, maxv = -FLT_MAX;
    for (int t = 0; t < Tc; t++) {
        // keep weights register-resident across the barrier-carrying loop
        #pragma unroll
        for (int j = 0; j < 52; j++) asm volatile("" : "+v"(w[j]));
        if (tid < NG) {
            float g = xg[t][tid];
            #pragma unroll
            for (int j = 0; j < 52; j += 4) {
                float4 hv = *(const float4*)&hs[j];   // broadcast reads
                g += hv.x * w[j] + hv.y * w[j+1] + hv.z * w[j+2] + hv.w * w[j+3];
            }
            // activation in the wide phase (each row knows its nonlinearity)
            gs[tid] = istanh ? tanh_fast(g) : sigmoid_fast(g);
        }
        __syncthreads();
        if (tid < Dc) {
            float si = gs[tid];
            float sf = gs[tid + 50];
            float tg = gs[tid + 100];
            float so = gs[tid + 150];
            c = sf * c + si * tg;
            float h = so * tanh_fast(c);
            hs[tid] = h;
            if (t < len) maxv = fmaxf(maxv, h);       // ragged max
        }
        __syncthreads();
    }
    if (tid < Dc)
        out[(size_t)n * OUTC + (Hh + WD) + dir * Dc + tid] = maxv;
}

// ================= kernel_word: word_reps masked max | embed =================
// grid 448: [0,384) word (8 l-rows per block), [384,448) embed.
// Own allocation, launch_bounds(256,2): the ~70-reg inner loop (24 mask +
// 16 acc + 16 load regs) can live in VGPRs instead of the fused kernel's
// 40-reg spill regime.

__global__ __launch_bounds__(256, 2) void kernel_word(
        const float* __restrict__ bert, const int* __restrict__ p2w,
        const float* __restrict__ minp,
        const int* __restrict__ word_ids, const float* __restrict__ word_table,
        float* __restrict__ out) {
    __shared__ __align__(16) char smem[16392];
    int blk = blockIdx.x, tid = threadIdx.x;

    if (blk < 384) {
        float (*sacc)[8][128] = (float (*)[8][128])smem;  // 4 waves * 8 rows * 128 = 16384B
        float* sminv = (float*)(smem + 16384);

        if (tid < 64) {
            float m = fminf(minp[tid], minp[tid + 64]);
            #pragma unroll
            for (int off = 32; off; off >>= 1) m = fminf(m, __shfl_down(m, off, 64));
            if (tid == 0) *sminv = m;
        }
        int idx = blk;                 // 0..383
        int hc  = idx % 6;             // h-chunk of 128
        int lt  = (idx / 6) & 31;      // l-tile of 8
        int b   = idx / 192;
        int l0  = lt * 8;
        int w    = tid >> 6;           // wave -> s range [w*96, w*96+96)
        int lane = tid & 63;
        int s0 = w * 96;

        // 96-bit row masks via 2 ballots -> 3 SGPRs per row
        const int* pm = p2w + ((size_t)(b * Ll + l0)) * Ss + s0;
        unsigned m0[8], m1[8], m2[8];
        #pragma unroll
        for (int r = 0; r < 8; r++) {
            unsigned long long b0 = __ballot(pm[r * Ss + lane] != 0);
            unsigned long long b1 = __ballot(lane < 32 ? (pm[r * Ss + 64 + lane] != 0) : false);
            m0[r] = __builtin_amdgcn_readfirstlane((unsigned)b0);
            m1[r] = __builtin_amdgcn_readfirstlane((unsigned)(b0 >> 32));
            m2[r] = __builtin_amdgcn_readfirstlane((unsigned)b1);
        }

        const float2* bb2 = (const float2*)(bert + (size_t)b * Ss * Hh) + hc * 64 + lane;
        float2 acc[8];
        #pragma unroll
        for (int r = 0; r < 8; r++) { acc[r].x = -FLT_MAX; acc[r].y = -FLT_MAX; }

        for (int jo = 0; jo < 96; jo += 8) {       // 12 groups of 8 loads in flight
            float2 v[8];
            #pragma unroll
            for (int k = 0; k < 8; k++) v[k] = bb2[(size_t)(s0 + jo + k) * 384];
            #pragma unroll
            for (int k = 0; k < 8; k++) {
                int j = jo + k;
                #pragma unroll
                for (int r = 0; r < 8; r++) {
                    unsigned bit = (j < 32 ? m0[r] >> j
                                 : j < 64 ? m1[r] >> (j - 32)
                                          : m2[r] >> (j - 64)) & 1u;
                    if (bit) {                     // wave-uniform scalar branch
                        acc[r].x = fmaxf(acc[r].x, v[k].x);
                        acc[r].y = fmaxf(acc[r].y, v[k].y);
                    }
                }
            }
        }
        #pragma unroll
        for (int r = 0; r < 8; r++)
            *(float2*)&sacc[w][r][lane * 2] = acc[r];
        __syncthreads();

        float mv = *sminv;
        for (int e = tid; e < 8 * 128; e += 256) {
            int r = e >> 7, cx = e & 127;
            float m = fmaxf(fmaxf(sacc[0][r][cx], sacc[1][r][cx]),
                            fmaxf(sacc[2][r][cx], sacc[3][r][cx]));
            if (m == -FLT_MAX) m = mv;             // fully-masked row -> global min fill
            out[((size_t)(b * Ll + l0 + r)) * OUTC + hc * 128 + cx] = m;
        }
    } else {
        // ---------------- word embedding gather ----------------
        for (int i = (blk - 384) * 256 + tid; i < Bb * Ll * WD; i += 64 * 256) {
            int bl = i / WD, d = i - bl * WD;
            out[(size_t)bl * OUTC + Hh + d] = word_table[(size_t)word_ids[bl] * WD + d];
        }
    }
}

extern "C" void kernel_launch(void* const* d_in, const int* in_sizes, int n_in,
                              void* d_out, int out_size, void* d_ws, size_t ws_size,
                              hipStream_t stream) {
    const float* bert       = (const float*)d_in[0];
    const int*   p2w        = (const int*)d_in[1];
    const int*   word_ids   = (const int*)d_in[2];
    const int*   char_count = (const int*)d_in[3];
    const int*   char_ids   = (const int*)d_in[4];
    // d_in[5] token_masks_char: consistent with char_count, unused
    const float* word_table = (const float*)d_in[6];
    const float* char_table = (const float*)d_in[7];
    const float* Wih_f = (const float*)d_in[8];
    const float* Whh_f = (const float*)d_in[9];
    const float* bih_f = (const float*)d_in[10];
    const float* bhh_f = (const float*)d_in[11];
    const float* Wih_b = (const float*)d_in[12];
    const float* Whh_b = (const float*)d_in[13];
    const float* bih_b = (const float*)d_in[14];
    const float* bhh_b = (const float*)d_in[15];
    float* out = (float*)d_out;

    float* minp = (float*)d_ws;          // 128 floats
    float* xpt  = minp + 128;            // 2*128*200 floats

    kernel1<<<144, 256, 0, stream>>>(
        bert, char_table, Wih_f, bih_f, bhh_f, Wih_b, bih_b, bhh_b,
        minp, xpt);
    kernel_lstm<<<1024, 256, 0, stream>>>(
        char_ids, char_count, Whh_f, Whh_b, xpt, out);
    kernel_word<<<448, 256, 0, stream>>>(
        bert, p2w, minp, word_ids, word_table, out);
}

// Round 7
// 128.675 us; speedup vs baseline: 1.2774x; 1.2774x over previous
//
#include <hip/hip_runtime.h>
#include <float.h>

#define Bb 2
#define Ll 256
#define Ss 384
#define Hh 768
#define Tc 16
#define Dc 50
#define WD 100
#define CV 128
#define NG 200     // 4*Dc gates
#define OUTC 968   // H + WD + 2*Dc

// ws layout (floats):
//   [0, 128)      minv partials
//   [128, ...)    xproj table [2][128][200], bias folded in

__device__ inline float tanh_fast(float x) {
    float e = __expf(2.f * x);
    return 1.f - 2.f / (e + 1.f);
}
__device__ inline float sigmoid_fast(float x) {
    return 1.f / (1.f + __expf(-x));
}

// ================= kernel 1: min partials | xproj =================
// grid 144: [0,128) min, [128,144) xproj

__global__ __launch_bounds__(256) void kernel1(
        const float* __restrict__ bert, const float* __restrict__ char_table,
        const float* __restrict__ Wih_f, const float* __restrict__ bih_f, const float* __restrict__ bhh_f,
        const float* __restrict__ Wih_b, const float* __restrict__ bih_b, const float* __restrict__ bhh_b,
        float* __restrict__ minp, float* __restrict__ xpt) {
    int blk = blockIdx.x, tid = threadIdx.x;
    if (blk < 128) {
        const int n4 = (Bb * Ss * Hh) / 4;       // 147456 float4
        const float4* b4 = (const float4*)bert;
        float m = FLT_MAX;
        for (int i = blk * 256 + tid; i < n4; i += 128 * 256) {
            float4 v = b4[i];
            m = fminf(m, fminf(fminf(v.x, v.y), fminf(v.z, v.w)));
        }
        #pragma unroll
        for (int off = 32; off; off >>= 1) m = fminf(m, __shfl_down(m, off, 64));
        __shared__ float red[4];
        if ((tid & 63) == 0) red[tid >> 6] = m;
        __syncthreads();
        if (tid == 0) minp[blk] = fminf(fminf(red[0], red[1]), fminf(red[2], red[3]));
    } else {
        int idx = blk - 128;            // dir*8 + cid-chunk
        int dir = idx >> 3, c0 = (idx & 7) * 16;
        const float* Wih = dir ? Wih_b : Wih_f;
        const float* bih = dir ? bih_b : bih_f;
        const float* bhh = dir ? bhh_b : bhh_f;
        __shared__ float ct[16][Dc];
        for (int e = tid; e < 16 * Dc; e += 256)
            ((float*)ct)[e] = char_table[c0 * Dc + e];
        __syncthreads();
        if (tid < NG) {
            float w[Dc];
            #pragma unroll
            for (int j = 0; j < Dc; j++) w[j] = Wih[tid * Dc + j];
            float bias = bih[tid] + bhh[tid];
            for (int cid = 0; cid < 16; cid++) {
                float a = bias;
                #pragma unroll
                for (int j = 0; j < Dc; j++) a += w[j] * ct[cid][j];
                xpt[(dir * CV + c0 + cid) * NG + tid] = a;
            }
        }
    }
}

// ================= kernel_lstm: char bi-LSTM =================
// grid 1024: n = blk>>1, dir = blk&1. (unchanged from round 6 -- measured
// ~20 us by subtraction; the word kernel was the pole at 56 us)

__global__ __launch_bounds__(256, 4) void kernel_lstm(
        const int* __restrict__ char_ids, const int* __restrict__ char_count,
        const float* __restrict__ Whh_f, const float* __restrict__ Whh_b,
        const float* __restrict__ xpt, float* __restrict__ out) {
    __shared__ __align__(16) char smem[13888];
    int blk = blockIdx.x, tid = threadIdx.x;

    float (*xg)[NG] = (float (*)[NG])smem;            // 16*200*4 = 12800
    float* gs  = (float*)(smem + 12800);              // 800
    float* hs  = (float*)(smem + 13600);              // 208 (52 floats)
    int*   scid = (int*)(smem + 13808);               // 64

    int n = blk >> 1, dir = blk & 1;
    const float* Whh = dir ? Whh_b : Whh_f;

    int len = char_count[n];
    if (len < 1) len = 1;
    if (tid < Tc) {
        int t = tid;
        int st = dir ? (t < len ? len - 1 - t : t) : t;   // bwd: reverse valid prefix
        scid[t] = char_ids[n * Tc + st];
    }
    if (tid < 52) hs[tid] = 0.f;
    __syncthreads();

    // stage xproj rows as float4 (row stride 200 floats = 800B, 16B aligned)
    for (int e = tid; e < Tc * (NG / 4); e += 256) {
        int t = e / 50, q = e - t * 50;
        ((float4*)xg[t])[q] = ((const float4*)&xpt[(dir * CV + scid[t]) * NG])[q];
    }
    // recurrent weight row -> regs, defined for ALL lanes (clamped row)
    int wrow = tid < NG ? tid : NG - 1;
    bool istanh = (tid >= 100 && tid < 150);          // cell-gate rows
    float w[52];
    #pragma unroll
    for (int j = 0; j < Dc; j++) w[j] = Whh[wrow * Dc + j];
    w[50] = 0.f; w[51] = 0.f;
    __syncthreads();

    float c = 0.f, maxv = -FLT_MAX;
    for (int t = 0; t < Tc; t++) {
        // keep weights register-resident across the barrier-carrying loop
        #pragma unroll
        for (int j = 0; j < 52; j++) asm volatile("" : "+v"(w[j]));
        if (tid < NG) {
            float g = xg[t][tid];
            #pragma unroll
            for (int j = 0; j < 52; j += 4) {
                float4 hv = *(const float4*)&hs[j];   // broadcast reads
                g += hv.x * w[j] + hv.y * w[j+1] + hv.z * w[j+2] + hv.w * w[j+3];
            }
            // activation in the wide phase (each row knows its nonlinearity)
            gs[tid] = istanh ? tanh_fast(g) : sigmoid_fast(g);
        }
        __syncthreads();
        if (tid < Dc) {
            float si = gs[tid];
            float sf = gs[tid + 50];
            float tg = gs[tid + 100];
            float so = gs[tid + 150];
            c = sf * c + si * tg;
            float h = so * tanh_fast(c);
            hs[tid] = h;
            if (t < len) maxv = fmaxf(maxv, h);       // ragged max
        }
        __syncthreads();
    }
    if (tid < Dc)
        out[(size_t)n * OUTC + (Hh + WD) + dir * Dc + tid] = maxv;
}

// ================= kernel_word: word_reps masked max | embed =================
// grid 448: [0,384) word (8 l-rows per block), [384,448) embed.
// BRANCHLESS masked max: the previous per-(k,r) scalar-branch formulation
// (runtime-shift bit extract + s_cbranch, ~6k SALU ops + 768 branches/wave)
// saturated the ONE per-CU scalar unit -> 56 us at 20% VALUBusy. Masks are
// now staged in LDS as additive biases (0 / -FLT_MAX); the accumulate is
// pure VALU: acc = fmax(acc, v + bias). v + (-FLT_MAX) == -FLT_MAX exactly
// for |v| << ulp, so the -FLT_MAX sentinel semantics are preserved.

__global__ __launch_bounds__(256, 2) void kernel_word(
        const float* __restrict__ bert, const int* __restrict__ p2w,
        const float* __restrict__ minp,
        const int* __restrict__ word_ids, const float* __restrict__ word_table,
        float* __restrict__ out) {
    __shared__ __align__(16) float sm[Ss][8];         // mask bias [s][row], 12288 B
    __shared__ __align__(16) float sacc[4][8][128];   // 16384 B
    __shared__ float sminv;
    int blk = blockIdx.x, tid = threadIdx.x;

    if (blk < 384) {
        int idx = blk;                 // 0..383
        int hc  = idx % 6;             // h-chunk of 128
        int lt  = (idx / 6) & 31;      // l-tile of 8
        int b   = idx / 192;
        int l0  = lt * 8;

        // stage mask bias: sm[s][r] = p2w[b][l0+r][s] ? 0 : -FLT_MAX
        // (r-fast element order -> consecutive-float LDS writes, conflict-free)
        const int* pm = p2w + ((size_t)(b * Ll + l0)) * Ss;
        for (int e = tid; e < 8 * Ss; e += 256) {
            int r = e & 7, s = e >> 3;
            sm[s][r] = pm[r * Ss + s] ? 0.f : -FLT_MAX;
        }
        if (tid < 64) {
            float m = fminf(minp[tid], minp[tid + 64]);
            #pragma unroll
            for (int off = 32; off; off >>= 1) m = fminf(m, __shfl_down(m, off, 64));
            if (tid == 0) sminv = m;
        }
        __syncthreads();

        int w    = tid >> 6;           // wave -> s range [w*96, w*96+96)
        int lane = tid & 63;
        int s0 = w * 96;

        const float2* bb2 = (const float2*)(bert + (size_t)b * Ss * Hh) + hc * 64 + lane;
        float2 acc[8];
        #pragma unroll
        for (int r = 0; r < 8; r++) { acc[r].x = -FLT_MAX; acc[r].y = -FLT_MAX; }

        for (int jo = 0; jo < 96; jo += 8) {       // 8 loads in flight per group
            float2 v[8];
            #pragma unroll
            for (int k = 0; k < 8; k++) v[k] = bb2[(size_t)(s0 + jo + k) * 384];
            #pragma unroll
            for (int k = 0; k < 8; k++) {
                int j = s0 + jo + k;
                float4 q0 = *(const float4*)&sm[j][0];   // broadcast, rows 0..3
                float4 q1 = *(const float4*)&sm[j][4];   // broadcast, rows 4..7
                acc[0].x = fmaxf(acc[0].x, v[k].x + q0.x);
                acc[0].y = fmaxf(acc[0].y, v[k].y + q0.x);
                acc[1].x = fmaxf(acc[1].x, v[k].x + q0.y);
                acc[1].y = fmaxf(acc[1].y, v[k].y + q0.y);
                acc[2].x = fmaxf(acc[2].x, v[k].x + q0.z);
                acc[2].y = fmaxf(acc[2].y, v[k].y + q0.z);
                acc[3].x = fmaxf(acc[3].x, v[k].x + q0.w);
                acc[3].y = fmaxf(acc[3].y, v[k].y + q0.w);
                acc[4].x = fmaxf(acc[4].x, v[k].x + q1.x);
                acc[4].y = fmaxf(acc[4].y, v[k].y + q1.x);
                acc[5].x = fmaxf(acc[5].x, v[k].x + q1.y);
                acc[5].y = fmaxf(acc[5].y, v[k].y + q1.y);
                acc[6].x = fmaxf(acc[6].x, v[k].x + q1.z);
                acc[6].y = fmaxf(acc[6].y, v[k].y + q1.z);
                acc[7].x = fmaxf(acc[7].x, v[k].x + q1.w);
                acc[7].y = fmaxf(acc[7].y, v[k].y + q1.w);
            }
        }
        #pragma unroll
        for (int r = 0; r < 8; r++)
            *(float2*)&sacc[w][r][lane * 2] = acc[r];
        __syncthreads();

        float mv = sminv;
        for (int e = tid; e < 8 * 128; e += 256) {
            int r = e >> 7, cx = e & 127;
            float m = fmaxf(fmaxf(sacc[0][r][cx], sacc[1][r][cx]),
                            fmaxf(sacc[2][r][cx], sacc[3][r][cx]));
            if (m == -FLT_MAX) m = mv;             // fully-masked row -> global min fill
            out[((size_t)(b * Ll + l0 + r)) * OUTC + hc * 128 + cx] = m;
        }
    } else {
        // ---------------- word embedding gather ----------------
        for (int i = (blk - 384) * 256 + tid; i < Bb * Ll * WD; i += 64 * 256) {
            int bl = i / WD, d = i - bl * WD;
            out[(size_t)bl * OUTC + Hh + d] = word_table[(size_t)word_ids[bl] * WD + d];
        }
    }
}

extern "C" void kernel_launch(void* const* d_in, const int* in_sizes, int n_in,
                              void* d_out, int out_size, void* d_ws, size_t ws_size,
                              hipStream_t stream) {
    const float* bert       = (const float*)d_in[0];
    const int*   p2w        = (const int*)d_in[1];
    const int*   word_ids   = (const int*)d_in[2];
    const int*   char_count = (const int*)d_in[3];
    const int*   char_ids   = (const int*)d_in[4];
    // d_in[5] token_masks_char: consistent with char_count, unused
    const float* word_table = (const float*)d_in[6];
    const float* char_table = (const float*)d_in[7];
    const float* Wih_f = (const float*)d_in[8];
    const float* Whh_f = (const float*)d_in[9];
    const float* bih_f = (const float*)d_in[10];
    const float* bhh_f = (const float*)d_in[11];
    const float* Wih_b = (const float*)d_in[12];
    const float* Whh_b = (const float*)d_in[13];
    const float* bih_b = (const float*)d_in[14];
    const float* bhh_b = (const float*)d_in[15];
    float* out = (float*)d_out;

    float* minp = (float*)d_ws;          // 128 floats
    float* xpt  = minp + 128;            // 2*128*200 floats

    kernel1<<<144, 256, 0, stream>>>(
        bert, char_table, Wih_f, bih_f, bhh_f, Wih_b, bih_b, bhh_b,
        minp, xpt);
    kernel_lstm<<<1024, 256, 0, stream>>>(
        char_ids, char_count, Whh_f, Whh_b, xpt, out);
    kernel_word<<<448, 256, 0, stream>>>(
        bert, p2w, minp, word_ids, word_table, out);
}